// Round 1
// baseline (628.248 us; speedup 1.0000x reference)
//
#include <hip/hip_runtime.h>
#include <hip/hip_bf16.h>
#include <cstdint>

// MoE SwiGLU MLP, routed top-2, bf16 MFMA path.
// T=2048 tokens, H=1024, F=4096, E=8, K=2 -> 4096 pairs, 103 GFLOP.

typedef short short8 __attribute__((ext_vector_type(8)));
typedef float floatx4 __attribute__((ext_vector_type(4)));

#define H_DIM 1024
#define F_DIM 4096
#define N_EXP 8
#define T_TOK 2048
#define MCAP  5120   // 4096 pairs + 8*128 padding capacity

#define BM 128
#define BN 64
#define BK 32
#define LDT 40       // LDS tile row length (32 + 8 pad) in bf16 elems -> 80B stride, 2-way max bank alias (free)

struct Meta {
  int cnt[N_EXP];
  int cursor[N_EXP];
  int poff[N_EXP + 1];
  int pad0;
  int pair_token[MCAP];
  float pair_w[MCAP];
  int token_pair[2 * T_TOK];
  int tok_e[2 * T_TOK];
  float tok_w[2 * T_TOK];
};

__device__ __forceinline__ unsigned short f2b(float f) {
  unsigned int u = __float_as_uint(f);
  u = (u + 0x7fffu + ((u >> 16) & 1u)) >> 16;   // RNE
  return (unsigned short)u;
}
__device__ __forceinline__ float b2f(unsigned short h) {
  return __uint_as_float(((unsigned int)h) << 16);
}

__global__ void k_init(Meta* __restrict__ m) {
  int i = threadIdx.x;
  if (i < N_EXP) { m->cnt[i] = 0; m->cursor[i] = 0; }
}

// One wave per token: logits = x[t] @ gate_w, softmax, top2, softmax of the top2 PROBS.
__global__ __launch_bounds__(64)
void k_router(const float* __restrict__ x, const float* __restrict__ gw,
              Meta* __restrict__ m) {
  int t = blockIdx.x;
  int lane = threadIdx.x;
  const float* xr = x + (size_t)t * H_DIM;
  float acc[N_EXP];
#pragma unroll
  for (int e = 0; e < N_EXP; ++e) acc[e] = 0.f;
  for (int i = 0; i < H_DIM / 64; ++i) {
    int h = i * 64 + lane;
    float xv = xr[h];
    const float* g = gw + (size_t)h * N_EXP;
#pragma unroll
    for (int e = 0; e < N_EXP; ++e) acc[e] += xv * g[e];
  }
#pragma unroll
  for (int e = 0; e < N_EXP; ++e) {
    float v = acc[e];
    for (int off = 32; off; off >>= 1) v += __shfl_xor(v, off, 64);
    acc[e] = v;
  }
  if (lane == 0) {
    float mx = acc[0];
    for (int e = 1; e < N_EXP; ++e) mx = fmaxf(mx, acc[e]);
    float p[N_EXP];
    float s = 0.f;
    for (int e = 0; e < N_EXP; ++e) { p[e] = __expf(acc[e] - mx); s += p[e]; }
    float inv = 1.f / s;
    for (int e = 0; e < N_EXP; ++e) p[e] *= inv;
    int i1 = 0;
    for (int e = 1; e < N_EXP; ++e) if (p[e] > p[i1]) i1 = e;
    int i2 = (i1 == 0) ? 1 : 0;
    for (int e = 0; e < N_EXP; ++e) if (e != i1 && p[e] > p[i2]) i2 = e;
    // softmax over the two probabilities (matches reference: softmax(topk_p))
    float w1 = 1.f / (1.f + __expf(p[i2] - p[i1]));
    m->tok_e[2 * t] = i1;     m->tok_e[2 * t + 1] = i2;
    m->tok_w[2 * t] = w1;     m->tok_w[2 * t + 1] = 1.f - w1;
    atomicAdd(&m->cnt[i1], 1);
    atomicAdd(&m->cnt[i2], 1);
  }
}

// 128-aligned per-expert regions so every GEMM M-tile maps to exactly one expert.
__global__ void k_scan(Meta* __restrict__ m) {
  if (threadIdx.x == 0 && blockIdx.x == 0) {
    int o = 0;
    for (int e = 0; e < N_EXP; ++e) {
      m->poff[e] = o;
      o += ((m->cnt[e] + BM - 1) / BM) * BM;
    }
    m->poff[N_EXP] = o;
  }
}

__global__ void k_assign(Meta* __restrict__ m) {
  int t = blockIdx.x * blockDim.x + threadIdx.x;
  if (t >= T_TOK) return;
  for (int k = 0; k < 2; ++k) {
    int e = m->tok_e[2 * t + k];
    int idx = atomicAdd(&m->cursor[e], 1);
    int p = m->poff[e] + idx;
    m->pair_token[p] = t;
    m->pair_w[p] = m->tok_w[2 * t + k];
    m->token_pair[2 * t + k] = p;
  }
}

// Gather x rows into per-pair bf16 matrix; zero the pad rows.
__global__ __launch_bounds__(256)
void k_gather(const float* __restrict__ x, unsigned short* __restrict__ Xe,
              const Meta* __restrict__ m) {
  int r = blockIdx.x;
  if (r >= m->poff[N_EXP]) return;
  int e = 0;
#pragma unroll
  for (int i = 1; i < N_EXP; ++i) if (r >= m->poff[i]) e = i;
  bool real = (r - m->poff[e]) < m->cnt[e];
  int h = threadIdx.x * 4;
  ushort4 sv = {0, 0, 0, 0};
  if (real) {
    int t = m->pair_token[r];
    float4 f = *(const float4*)(x + (size_t)t * H_DIM + h);
    sv.x = f2b(f.x); sv.y = f2b(f.y); sv.z = f2b(f.z); sv.w = f2b(f.w);
  }
  *(ushort4*)(Xe + (size_t)r * H_DIM + h) = sv;
}

// Fused gate+up GEMM: A[r, f] = silu(Xe@Wg) * (Xe@Wu), bf16 out.
// Block = 256 thr = 4 waves (2x2), block tile 128x64, wave tile 64x32, K-step 32.
__global__ __launch_bounds__(256, 2)
void k_gemm_dual(const unsigned short* __restrict__ Xe,
                 const float* __restrict__ w_gate,
                 const float* __restrict__ w_up,
                 unsigned short* __restrict__ Aw,
                 const Meta* __restrict__ m) {
  __shared__ unsigned short As[BM * LDT];
  __shared__ unsigned short Bg[BN * LDT];
  __shared__ unsigned short Bu[BN * LDT];
  int tileM = blockIdx.y * BM;
  if (tileM >= m->poff[N_EXP]) return;
  int e = 0;
#pragma unroll
  for (int i = 1; i < N_EXP; ++i) if (tileM >= m->poff[i]) e = i;
  int n0 = blockIdx.x * BN;
  const float* Wg = w_gate + (size_t)e * H_DIM * F_DIM;
  const float* Wu = w_up   + (size_t)e * H_DIM * F_DIM;

  int tid = threadIdx.x;
  int lane = tid & 63;
  int wid = tid >> 6;
  int wm = (wid & 1) * 64;
  int wn = (wid >> 1) * 32;
  int lm = lane & 15;
  int quad = lane >> 4;

  floatx4 accG[4][2] = {};
  floatx4 accU[4][2] = {};

  for (int k0 = 0; k0 < H_DIM; k0 += BK) {
    // stage A (bf16, row-major k-contiguous): 128x32 = 512 16B chunks / 256 thr
    {
      int c = tid;
#pragma unroll
      for (int it = 0; it < 2; ++it, c += 256) {
        int row = c >> 2, kp = c & 3;
        *(uint4*)&As[row * LDT + kp * 8] =
            *(const uint4*)(Xe + (size_t)(tileM + row) * H_DIM + k0 + kp * 8);
      }
    }
    // stage B (fp32 k-major global -> bf16 n-major LDS), both matrices
    {
      int nn = tid & 63;
      int kh = tid >> 6;  // 0..3, 8 k each
      const float* sg = Wg + (size_t)(k0 + kh * 8) * F_DIM + n0 + nn;
      const float* su = Wu + (size_t)(k0 + kh * 8) * F_DIM + n0 + nn;
      short8 vg, vu;
#pragma unroll
      for (int j = 0; j < 8; ++j) {
        vg[j] = (short)f2b(sg[(size_t)j * F_DIM]);
        vu[j] = (short)f2b(su[(size_t)j * F_DIM]);
      }
      *(short8*)&Bg[nn * LDT + kh * 8] = vg;
      *(short8*)&Bu[nn * LDT + kh * 8] = vu;
    }
    __syncthreads();
    short8 a[4];
#pragma unroll
    for (int fm = 0; fm < 4; ++fm)
      a[fm] = *(const short8*)&As[(wm + fm * 16 + lm) * LDT + quad * 8];
#pragma unroll
    for (int fn = 0; fn < 2; ++fn) {
      short8 bg = *(const short8*)&Bg[(wn + fn * 16 + lm) * LDT + quad * 8];
      short8 bu = *(const short8*)&Bu[(wn + fn * 16 + lm) * LDT + quad * 8];
#pragma unroll
      for (int fm = 0; fm < 4; ++fm) {
        accG[fm][fn] = __builtin_amdgcn_mfma_f32_16x16x32_bf16(a[fm], bg, accG[fm][fn], 0, 0, 0);
        accU[fm][fn] = __builtin_amdgcn_mfma_f32_16x16x32_bf16(a[fm], bu, accU[fm][fn], 0, 0, 0);
      }
    }
    __syncthreads();
  }
  // epilogue: silu(g)*u, bf16. D layout: row=(lane>>4)*4+r, col=lane&15 (verified m89/m91)
#pragma unroll
  for (int fm = 0; fm < 4; ++fm)
#pragma unroll
    for (int fn = 0; fn < 2; ++fn)
#pragma unroll
      for (int r = 0; r < 4; ++r) {
        int row = tileM + wm + fm * 16 + quad * 4 + r;
        int col = n0 + wn + fn * 16 + lm;
        float g = accG[fm][fn][r];
        float u = accU[fm][fn][r];
        float s = g / (1.f + __expf(-g));
        Aw[(size_t)row * F_DIM + col] = f2b(s * u);
      }
}

// Down GEMM: Y = A @ Wd[e], K=4096, N=1024, bf16 out.
__global__ __launch_bounds__(256, 2)
void k_gemm_down(const unsigned short* __restrict__ Aw,
                 const float* __restrict__ w_down,
                 unsigned short* __restrict__ Y,
                 const Meta* __restrict__ m) {
  __shared__ unsigned short As[BM * LDT];
  __shared__ unsigned short Bs[BN * LDT];
  int tileM = blockIdx.y * BM;
  if (tileM >= m->poff[N_EXP]) return;
  int e = 0;
#pragma unroll
  for (int i = 1; i < N_EXP; ++i) if (tileM >= m->poff[i]) e = i;
  int n0 = blockIdx.x * BN;
  const float* W = w_down + (size_t)e * F_DIM * H_DIM;

  int tid = threadIdx.x;
  int lane = tid & 63;
  int wid = tid >> 6;
  int wm = (wid & 1) * 64;
  int wn = (wid >> 1) * 32;
  int lm = lane & 15;
  int quad = lane >> 4;

  floatx4 acc[4][2] = {};

  for (int k0 = 0; k0 < F_DIM; k0 += BK) {
    {
      int c = tid;
#pragma unroll
      for (int it = 0; it < 2; ++it, c += 256) {
        int row = c >> 2, kp = c & 3;
        *(uint4*)&As[row * LDT + kp * 8] =
            *(const uint4*)(Aw + (size_t)(tileM + row) * F_DIM + k0 + kp * 8);
      }
    }
    {
      int nn = tid & 63;
      int kh = tid >> 6;
      const float* s = W + (size_t)(k0 + kh * 8) * H_DIM + n0 + nn;
      short8 v;
#pragma unroll
      for (int j = 0; j < 8; ++j) v[j] = (short)f2b(s[(size_t)j * H_DIM]);
      *(short8*)&Bs[nn * LDT + kh * 8] = v;
    }
    __syncthreads();
    short8 a[4];
#pragma unroll
    for (int fm = 0; fm < 4; ++fm)
      a[fm] = *(const short8*)&As[(wm + fm * 16 + lm) * LDT + quad * 8];
#pragma unroll
    for (int fn = 0; fn < 2; ++fn) {
      short8 b = *(const short8*)&Bs[(wn + fn * 16 + lm) * LDT + quad * 8];
#pragma unroll
      for (int fm = 0; fm < 4; ++fm)
        acc[fm][fn] = __builtin_amdgcn_mfma_f32_16x16x32_bf16(a[fm], b, acc[fm][fn], 0, 0, 0);
    }
    __syncthreads();
  }
#pragma unroll
  for (int fm = 0; fm < 4; ++fm)
#pragma unroll
    for (int fn = 0; fn < 2; ++fn)
#pragma unroll
      for (int r = 0; r < 4; ++r) {
        int row = tileM + wm + fm * 16 + quad * 4 + r;
        int col = n0 + wn + fn * 16 + lm;
        Y[(size_t)row * H_DIM + col] = f2b(acc[fm][fn][r]);
      }
}

// out[t] = w0 * Y[p0] + w1 * Y[p1]  (fp32 out, no atomics, deterministic)
__global__ __launch_bounds__(256)
void k_combine(const unsigned short* __restrict__ Y, const Meta* __restrict__ m,
               float* __restrict__ out) {
  int t = blockIdx.x;
  int h = threadIdx.x * 4;
  int p0 = m->token_pair[2 * t];
  int p1 = m->token_pair[2 * t + 1];
  float w0 = m->pair_w[p0];
  float w1 = m->pair_w[p1];
  ushort4 y0 = *(const ushort4*)(Y + (size_t)p0 * H_DIM + h);
  ushort4 y1 = *(const ushort4*)(Y + (size_t)p1 * H_DIM + h);
  float4 o;
  o.x = w0 * b2f(y0.x) + w1 * b2f(y1.x);
  o.y = w0 * b2f(y0.y) + w1 * b2f(y1.y);
  o.z = w0 * b2f(y0.z) + w1 * b2f(y1.z);
  o.w = w0 * b2f(y0.w) + w1 * b2f(y1.w);
  *(float4*)(out + (size_t)t * H_DIM + h) = o;
}

extern "C" void kernel_launch(void* const* d_in, const int* in_sizes, int n_in,
                              void* d_out, int out_size, void* d_ws, size_t ws_size,
                              hipStream_t stream) {
  const float* x  = (const float*)d_in[0];
  const float* gw = (const float*)d_in[1];
  const float* wg = (const float*)d_in[2];
  const float* wu = (const float*)d_in[3];
  const float* wd = (const float*)d_in[4];
  float* out = (float*)d_out;

  // ws layout: Xe bf16 [5120][1024] | Aw bf16 [5120][4096] | Y bf16 [5120][1024] | Meta
  unsigned short* Xe = (unsigned short*)d_ws;
  unsigned short* Aw = Xe + (size_t)MCAP * H_DIM;
  unsigned short* Y  = Aw + (size_t)MCAP * F_DIM;
  Meta* m = (Meta*)(Y + (size_t)MCAP * H_DIM);

  k_init<<<1, 64, 0, stream>>>(m);
  k_router<<<T_TOK, 64, 0, stream>>>(x, gw, m);
  k_scan<<<1, 64, 0, stream>>>(m);
  k_assign<<<T_TOK / 256, 256, 0, stream>>>(m);
  k_gather<<<MCAP, 256, 0, stream>>>(x, Xe, m);
  k_gemm_dual<<<dim3(F_DIM / BN, MCAP / BM), 256, 0, stream>>>(Xe, wg, wu, Aw, m);
  k_gemm_down<<<dim3(H_DIM / BN, MCAP / BM), 256, 0, stream>>>(Aw, wd, Y, m);
  k_combine<<<T_TOK, 256, 0, stream>>>(Y, m, out);
}